// Round 15
// baseline (1268.476 us; speedup 1.0000x reference)
//
#include <hip/hip_runtime.h>
#include <math.h>

#define BB 32     // batch
#define TT 128    // time steps
#define NF 256    // input features
#define HH 512    // hidden
#define G3 1536   // 3*H
#define NWG 64    // GRU workgroups (column partition)

__device__ __forceinline__ float sigmoidf_(float x) { return 1.f / (1.f + __expf(-x)); }
__device__ __forceinline__ float tanh_fast(float x) {
    float e = __expf(2.f * x);
    return 1.f - 2.f * __builtin_amdgcn_rcpf(e + 1.f);
}
__device__ __forceinline__ float sel8_(float a0, float a1, float a2, float a3,
                                       float a4, float a5, float a6, float a7, int s) {
    float x0 = (s & 1) ? a1 : a0;
    float x1 = (s & 1) ? a3 : a2;
    float x2 = (s & 1) ? a5 : a4;
    float x3 = (s & 1) ? a7 : a6;
    float y0 = (s & 2) ? x1 : x0;
    float y1 = (s & 2) ? x3 : x2;
    return (s & 4) ? y1 : y0;
}

// ---------------- K0a: init h double buffer (transpose h0 -> [i][b]) ----------------
__global__ __launch_bounds__(256) void k_hinit(const float* __restrict__ h0,
                                               float* __restrict__ hg2) {
    int idx = blockIdx.x * 256 + threadIdx.x;   // 64 blocks -> 16384
    int i = idx & 511, b = idx >> 9;
    hg2[i * BB + b] = h0[b * HH + i];
}

// ---------------- K0b: pack rk into per-WG swizzled float4 blocks (r10 verbatim) ----------------
__global__ __launch_bounds__(256) void k_pack(const float* __restrict__ rk,
                                              float4* __restrict__ rk4) {
    int gidx = blockIdx.x * 256 + threadIdx.x;   // 1024 blocks -> 262144
    int wg = gidx >> 12;
    int idx = gidx & 4095;
    int k = idx >> 3, s = idx & 7;
    int jjL = s ^ (((k >> 7) & 3) << 1);
    const float* r = rk + (size_t)k * G3 + wg * 8 + jjL;
    rk4[gidx] = make_float4(r[0], r[512], r[1024], 0.f);
}

// ---------------- K1: mxT[t][j][b] — 512 blocks / 8 batches (r13 proven) ----------------
__global__ __launch_bounds__(256) void k_mx(const float* __restrict__ data,
                                            const float* __restrict__ gk,
                                            const float* __restrict__ bias_in,
                                            float* __restrict__ mxT) {
    __shared__ __align__(16) float xs[NF * 8];   // [k][bb]
    int bx = blockIdx.x;
    int t = bx >> 2, b0 = (bx & 3) * 8;
    int tid = threadIdx.x;
    for (int idx = tid; idx < 8 * NF; idx += 256) {
        int bb = idx >> 8, k = idx & 255;
        xs[k * 8 + bb] = data[((size_t)(b0 + bb) * TT + t) * NF + k];
    }
    __syncthreads();
    float acc[6][8];
#pragma unroll
    for (int jj = 0; jj < 6; jj++)
#pragma unroll
        for (int bb = 0; bb < 8; bb++) acc[jj][bb] = 0.f;

    for (int k = 0; k < NF; k++) {
        float4 xa = *(const float4*)&xs[k * 8];
        float4 xb = *(const float4*)&xs[k * 8 + 4];
        float xv[8] = {xa.x, xa.y, xa.z, xa.w, xb.x, xb.y, xb.z, xb.w};
#pragma unroll
        for (int jj = 0; jj < 6; jj++) {
            float g = gk[(size_t)k * G3 + jj * 256 + tid];
#pragma unroll
            for (int bb = 0; bb < 8; bb++) acc[jj][bb] += g * xv[bb];
        }
    }
#pragma unroll
    for (int jj = 0; jj < 6; jj++) {
        int j = jj * 256 + tid;
        float bi = bias_in[j];
#pragma unroll
        for (int bb = 0; bb < 8; bb++)
            mxT[((size_t)t * G3 + j) * BB + b0 + bb] = acc[jj][bb] + bi;   // [t][j][b]
    }
}

// ---------------- K2: ONE GRU STEP — (jj, bq-pair, ks8) map: 3 LDS reads / 24 FMA per k ----------------
// Thread: jj = tid>>5 (col), bqp = (tid>>3)&3 (batch octet bqp*8..+7), ks = tid&7 (64 k).
// h LDS swizzle: slot = quad ^ (k>>6 & 7)  -> h-reads 4-way (as before), w-reads 2-way (free).
// Butterfly 3 stages over ks lanes; sel8 picks batch = bqp*8 + ks. rk4 layout unchanged.
extern __shared__ float4 wl4_dyn[];   // 4096 float4 = 64 KB, r10 swizzled weight layout

__global__ __launch_bounds__(256, 1) void k_gstep(const float4* __restrict__ rk4,
                                                  const float* __restrict__ gbias,
                                                  const float* __restrict__ mxT,
                                                  float* __restrict__ hg2,
                                                  float* __restrict__ hs,
                                                  int t) {
    __shared__ __align__(16) float4 h4[HH * 8];   // 64 KB: slot = quad ^ (k>>6 & 7)
    const int tid = threadIdx.x;
    const int wg  = blockIdx.x;
    const int jj  = tid >> 5;          // 0..7 column within slice
    const int bqp = (tid >> 3) & 3;    // 0..3 batch octet
    const int ks  = tid & 7;           // 0..7 k-split (64 k each)
    const int i0  = wg * 8;
    const int i   = i0 + jj;
    const int batch = bqp * 8 + ks;

    // ---- stage weights: async global->LDS, linear dest (prepacked swizzle) ----
    {
        const float4* src = rk4 + (size_t)wg * 4096;
#pragma unroll
        for (int it = 0; it < 16; it++) {
            int idx = it * 256 + tid;
            __builtin_amdgcn_global_load_lds(
                (const __attribute__((address_space(1))) void*)(src + idx),
                (__attribute__((address_space(3))) void*)&wl4_dyn[idx], 16, 0, 0);
        }
    }
    // ---- stage h: linear LDS dest, pre-swizzled global source: q = s ^ (k>>6 & 7) ----
    {
        const float4* hgr = (const float4*)(hg2 + (t & 1) * (HH * BB));
#pragma unroll
        for (int it = 0; it < 16; it++) {
            int idx = it * 256 + tid;
            int sidx = (idx & ~7) | ((idx & 7) ^ ((idx >> 9) & 7));
            __builtin_amdgcn_global_load_lds(
                (const __attribute__((address_space(1))) void*)(hgr + sidx),
                (__attribute__((address_space(3))) void*)&h4[idx], 16, 0, 0);
        }
    }
    const float* brec = gbias + G3;
    const float bz = brec[i], br_ = brec[512 + i], bh = brec[1024 + i];
    __syncthreads();   // drains vmcnt for global_load_lds

    // mx loads — coalesced from mxT[t][j][b]
    const float* mxc = mxT + (size_t)t * G3 * BB;
    float mz = mxc[(size_t)i * BB + batch];
    float mr = mxc[(size_t)(512 + i) * BB + batch];
    float mh = mxc[(size_t)(1024 + i) * BB + batch];

    // ---- inner: 64 k per thread, 3 b128 reads + 24 FMA per k ----
    float az[8], ar[8], ah[8];
#pragma unroll
    for (int e = 0; e < 8; e++) { az[e] = 0.f; ar[e] = 0.f; ah[e] = 0.f; }

    const float4* wp  = wl4_dyn + (size_t)ks * 512 + (jj ^ (((ks >> 1) & 3) << 1));
    const float4* hpA = h4 + (size_t)ks * 512 + ((bqp << 1) ^ ks);        // quad 2bqp
    const float4* hpB = h4 + (size_t)ks * 512 + (((bqp << 1) | 1) ^ ks);  // quad 2bqp+1
#pragma unroll 4
    for (int kk = 0; kk < 64; kk++) {
        float4 w  = wp[kk * 8];     // {wz,wr,wc,_} col jj, k = ks*64+kk (8-lane broadcast)
        float4 ha = hpA[kk * 8];    // batches bqp*8 .. +3
        float4 hb = hpB[kk * 8];    // batches bqp*8+4 .. +7
        az[0] += w.x * ha.x; az[1] += w.x * ha.y; az[2] += w.x * ha.z; az[3] += w.x * ha.w;
        az[4] += w.x * hb.x; az[5] += w.x * hb.y; az[6] += w.x * hb.z; az[7] += w.x * hb.w;
        ar[0] += w.y * ha.x; ar[1] += w.y * ha.y; ar[2] += w.y * ha.z; ar[3] += w.y * ha.w;
        ar[4] += w.y * hb.x; ar[5] += w.y * hb.y; ar[6] += w.y * hb.z; ar[7] += w.y * hb.w;
        ah[0] += w.z * ha.x; ah[1] += w.z * ha.y; ah[2] += w.z * ha.z; ah[3] += w.z * ha.w;
        ah[4] += w.z * hb.x; ah[5] += w.z * hb.y; ah[6] += w.z * hb.z; ah[7] += w.z * hb.w;
    }

    // ---- butterfly over ks lanes (masks 1,2,4): full-k sums in every lane ----
#pragma unroll
    for (int m = 1; m <= 4; m <<= 1) {
#pragma unroll
        for (int e = 0; e < 8; e++) {
            az[e] += __shfl_xor(az[e], m);
            ar[e] += __shfl_xor(ar[e], m);
            ah[e] += __shfl_xor(ah[e], m);
        }
    }

    // ---- this thread finishes (col i, batch = bqp*8 + ks): pick e = ks ----
    float azt = sel8_(az[0], az[1], az[2], az[3], az[4], az[5], az[6], az[7], ks);
    float art = sel8_(ar[0], ar[1], ar[2], ar[3], ar[4], ar[5], ar[6], ar[7], ks);
    float aht = sel8_(ah[0], ah[1], ah[2], ah[3], ah[4], ah[5], ah[6], ah[7], ks);

    float z = sigmoidf_(mz + azt + bz);
    float r = sigmoidf_(mr + art + br_);
    float c = tanhf(mh + r * (aht + bh));
    int hq = ((bqp << 1) + (ks >> 2)) ^ ((i >> 6) & 7);   // slot of quad batch>>2 at k=i
    float hold = ((const float*)&h4[(size_t)i * 8 + hq])[ks & 3];
    float hn = z * hold + (1.f - z) * c;

    hg2[((t + 1) & 1) * (HH * BB) + i * BB + batch] = hn;   // coalesced

    // ---- hs store via LDS transpose (weights consumed -> reuse wl4_dyn region) ----
    __syncthreads();
    float* hstage = (float*)wl4_dyn;
    hstage[jj * 36 + batch] = hn;           // conflict-free (pad 36)
    __syncthreads();
    {
        int b2 = tid >> 3, ii = tid & 7;    // 32B-segment stores
        hs[((size_t)t * BB + b2) * HH + i0 + ii] = hstage[ii * 36 + b2];
    }
}

// ---------------- K3: sx[b][u][n] (upfront, r10 verbatim) ----------------
__global__ __launch_bounds__(256) void k_sx(const float* __restrict__ data,
                                            const float* __restrict__ w1,
                                            const float* __restrict__ w1b,
                                            float* __restrict__ sx) {
    int bx = blockIdx.x;
    int b = bx >> 4, ug = bx & 15;
    int n = threadIdx.x;
    float acc[8] = {0, 0, 0, 0, 0, 0, 0, 0};
    const float* dp = data + (size_t)b * TT * NF + n;
    for (int t = 0; t < TT; t++) {
        float x = dp[(size_t)t * NF];
#pragma unroll
        for (int uu = 0; uu < 8; uu++) acc[uu] += x * w1[t * TT + ug * 8 + uu];
    }
#pragma unroll
    for (int uu = 0; uu < 8; uu++) {
        int u = ug * 8 + uu;
        sx[((size_t)b * TT + u) * NF + n] = acc[uu] + w1b[u];
    }
}

// ---------------- K4: hp[r][u] = hs[r][:] @ w2 + w2b  (r10 verbatim) ----------------
__global__ __launch_bounds__(256) void k_hp(const float* __restrict__ hs,
                                            const float* __restrict__ w2,
                                            const float* __restrict__ w2b,
                                            float* __restrict__ hp) {
    __shared__ float hsl[8 * HH];   // 16KB
    int r0 = blockIdx.x * 8;
    int tid = threadIdx.x;
    for (int idx = tid; idx < 8 * HH; idx += 256)
        hsl[idx] = hs[(size_t)r0 * HH + idx];
    __syncthreads();
    int u = tid & 127, rh = tid >> 7;
    float acc[4] = {0, 0, 0, 0};
    for (int k = 0; k < HH; k++) {
        float w = w2[k * TT + u];
#pragma unroll
        for (int rr = 0; rr < 4; rr++) acc[rr] += hsl[(rh * 4 + rr) * HH + k] * w;
    }
    float wb = w2b[u];
#pragma unroll
    for (int rr = 0; rr < 4; rr++)
        hp[(size_t)(r0 + rh * 4 + rr) * TT + u] = acc[rr] + wb;
}

// ---------------- K5: fused score + softmax + output (rcp tanh + unroll) ----------------
__global__ __launch_bounds__(256) void k_attn(const float* __restrict__ data,
                                              const float* __restrict__ sx,
                                              const float* __restrict__ hp,
                                              const float* __restrict__ v_w,
                                              const float* __restrict__ v_b,
                                              float* __restrict__ out) {
    __shared__ float hv[TT];
    __shared__ float vv[TT];
    __shared__ float red[8];
    int r = blockIdx.x;
    int b = r & 31;
    int n = threadIdx.x;
    if (n < TT) {
        hv[n] = hp[(size_t)r * TT + n];
        vv[n] = v_w[n];
    }
    __syncthreads();
    float s = v_b[0];
    const float* sxp = sx + (size_t)b * TT * NF + n;
#pragma unroll 4
    for (int u = 0; u < TT; u++) {
        float e = tanh_fast(sxp[(size_t)u * NF] + hv[u]);
        s += vv[u] * e;
    }
    float m = s;
#pragma unroll
    for (int off = 32; off >= 1; off >>= 1) m = fmaxf(m, __shfl_xor(m, off));
    int lane = n & 63, wid = n >> 6;
    if (lane == 0) red[wid] = m;
    __syncthreads();
    float bm = fmaxf(fmaxf(red[0], red[1]), fmaxf(red[2], red[3]));
    float p = __expf(s - bm);
    float ps = p;
#pragma unroll
    for (int off = 32; off >= 1; off >>= 1) ps += __shfl_xor(ps, off);
    if (lane == 0) red[4 + wid] = ps;
    __syncthreads();
    float denom = red[4] + red[5] + red[6] + red[7];
    float alpha = p / denom;
    size_t idx = (size_t)r * NF + n;
    out[idx] = data[idx] * alpha;
}

extern "C" void kernel_launch(void* const* d_in, const int* in_sizes, int n_in,
                              void* d_out, int out_size, void* d_ws, size_t ws_size,
                              hipStream_t stream) {
    const float* data = (const float*)d_in[0];
    const float* h0   = (const float*)d_in[1];
    const float* gk   = (const float*)d_in[2];
    const float* rk   = (const float*)d_in[3];
    const float* gb   = (const float*)d_in[4];
    const float* w1   = (const float*)d_in[5];
    const float* w1b  = (const float*)d_in[6];
    const float* w2   = (const float*)d_in[7];
    const float* w2b  = (const float*)d_in[8];
    const float* vw   = (const float*)d_in[9];
    const float* vb   = (const float*)d_in[10];
    float* out = (float*)d_out;

    float* ws  = (float*)d_ws;
    float* mxT = ws;                    // 128*1536*32 = 6291456  ([t][j][b])
    float* hs  = mxT + 6291456;         // 128*32*512  = 2097152
    float* sxb = hs + 2097152;          // 32*128*256  = 1048576
    float* hpb = sxb + 1048576;         // 128*32*128  = 524288
    float* hg2 = hpb + 524288;          // 2*512*32    = 32768
    float4* rk4 = (float4*)(hg2 + 32768);   // 262144 float4 = 4 MB

    k_hinit<<<64, 256, 0, stream>>>(h0, hg2);
    k_pack<<<1024, 256, 0, stream>>>(rk, rk4);
    k_mx<<<512, 256, 0, stream>>>(data, gk, gb, mxT);

    for (int t = 0; t < TT; t++)
        k_gstep<<<NWG, 256, 65536, stream>>>(rk4, gb, mxT, hg2, hs, t);

    k_sx<<<512, 256, 0, stream>>>(data, w1, w1b, sxb);
    k_hp<<<512, 256, 0, stream>>>(hs, w2, w2b, hpb);
    k_attn<<<4096, 256, 0, stream>>>(data, sxb, hpb, vw, vb, out);
}

// Round 16
// 1175.938 us; speedup vs baseline: 1.0787x; 1.0787x over previous
//
#include <hip/hip_runtime.h>
#include <math.h>

#define BB 32     // batch
#define TT 128    // time steps
#define NF 256    // input features
#define HH 512    // hidden
#define G3 1536   // 3*H
#define NWG 64    // GRU workgroups (column partition)

__device__ __forceinline__ float sigmoidf_(float x) { return 1.f / (1.f + __expf(-x)); }
__device__ __forceinline__ float tanh_fast(float x) {
    float e = __expf(2.f * x);
    return 1.f - 2.f * __builtin_amdgcn_rcpf(e + 1.f);
}
__device__ __forceinline__ float sel4_(float a0, float a1, float a2, float a3, int s) {
    float s01 = (s & 1) ? a1 : a0;
    float s23 = (s & 1) ? a3 : a2;
    return (s & 2) ? s23 : s01;
}

// ---------------- K0: merged pack(rk->rk4, blocks 0..1023) + hinit (blocks 1024..1087) ----------------
__global__ __launch_bounds__(256) void k_packinit(const float* __restrict__ rk,
                                                  float4* __restrict__ rk4,
                                                  const float* __restrict__ h0,
                                                  float* __restrict__ hg2) {
    int bid = blockIdx.x;
    if (bid < 1024) {
        int gidx = bid * 256 + threadIdx.x;   // 262144
        int wg = gidx >> 12;
        int idx = gidx & 4095;
        int k = idx >> 3, s = idx & 7;
        int jjL = s ^ (((k >> 7) & 3) << 1);
        const float* r = rk + (size_t)k * G3 + wg * 8 + jjL;
        rk4[gidx] = make_float4(r[0], r[512], r[1024], 0.f);
    } else {
        int idx = (bid - 1024) * 256 + threadIdx.x;   // 16384
        int i = idx & 511, b = idx >> 9;
        hg2[i * BB + b] = h0[b * HH + i];
    }
}

// ---------------- K1: mxT[t][j][b] — j split 3 ways: 1536 blocks, 6/CU (latency amortized) ----------------
// bx -> t = bx/12, bg = (bx%12)/3, jth = bx%3. Thread: 2 j = jth*512 + jj*256 + tid.
// k-loop order identical to r14 -> bit-identical mxT.
__global__ __launch_bounds__(256) void k_mx(const float* __restrict__ data,
                                            const float* __restrict__ gk,
                                            const float* __restrict__ bias_in,
                                            float* __restrict__ mxT) {
    __shared__ __align__(16) float xs[NF * 8];   // [k][bb]
    int bx = blockIdx.x;
    int t = bx / 12;
    int rem = bx - t * 12;
    int bg = rem / 3;
    int jth = rem - bg * 3;
    int b0 = bg * 8;
    int tid = threadIdx.x;
    for (int idx = tid; idx < 8 * NF; idx += 256) {
        int bb = idx >> 8, k = idx & 255;
        xs[k * 8 + bb] = data[((size_t)(b0 + bb) * TT + t) * NF + k];
    }
    __syncthreads();
    float acc[2][8];
#pragma unroll
    for (int jj = 0; jj < 2; jj++)
#pragma unroll
        for (int bb = 0; bb < 8; bb++) acc[jj][bb] = 0.f;

    const float* gkc = gk + jth * 512 + tid;
    for (int k = 0; k < NF; k++) {
        float4 xa = *(const float4*)&xs[k * 8];
        float4 xb = *(const float4*)&xs[k * 8 + 4];
        float xv[8] = {xa.x, xa.y, xa.z, xa.w, xb.x, xb.y, xb.z, xb.w};
#pragma unroll
        for (int jj = 0; jj < 2; jj++) {
            float g = gkc[(size_t)k * G3 + jj * 256];
#pragma unroll
            for (int bb = 0; bb < 8; bb++) acc[jj][bb] += g * xv[bb];
        }
    }
#pragma unroll
    for (int jj = 0; jj < 2; jj++) {
        int j = jth * 512 + jj * 256 + tid;
        float bi = bias_in[j];
#pragma unroll
        for (int bb = 0; bb < 8; bb++)
            mxT[((size_t)t * G3 + j) * BB + b0 + bb] = acc[jj][bb] + bi;   // [t][j][b]
    }
}

// ---------------- K2: ONE GRU STEP — r14 proven kernel VERBATIM ----------------
extern __shared__ float4 wl4_dyn[];   // 4096 float4 = 64 KB, r10 swizzled weight layout

__global__ __launch_bounds__(256, 1) void k_gstep(const float4* __restrict__ rk4,
                                                  const float* __restrict__ gbias,
                                                  const float* __restrict__ mxT,
                                                  float* __restrict__ hg2,
                                                  float* __restrict__ hs,
                                                  int t) {
    __shared__ __align__(16) float4 h4[HH * 8];   // 64 KB: h[k][batch-quad], swizzled
    const int tid = threadIdx.x;
    const int wg  = blockIdx.x;
    const int jj  = tid >> 5;          // 0..7 column within slice
    const int bq  = (tid >> 2) & 7;    // 0..7 batch quad
    const int ks  = tid & 3;           // 0..3 k-split (128 k each)
    const int i0  = wg * 8;
    const int i   = i0 + jj;
    const int batch = bq * 4 + ks;
    const int jjs = jj ^ (ks << 1);    // swizzled weight slot for this thread's k-range
    const int bqs = bq ^ (ks << 1);    // swizzled h slot for this thread's k-range

    // ---- stage weights: async global->LDS, linear dest (prepacked swizzle) ----
    {
        const float4* src = rk4 + (size_t)wg * 4096;
#pragma unroll
        for (int it = 0; it < 16; it++) {
            int idx = it * 256 + tid;
            __builtin_amdgcn_global_load_lds(
                (const __attribute__((address_space(1))) void*)(src + idx),
                (__attribute__((address_space(3))) void*)&wl4_dyn[idx], 16, 0, 0);
        }
    }
    // ---- stage h: linear LDS dest, PRE-SWIZZLED global source (m173 pattern) ----
    {
        const float4* hgr = (const float4*)(hg2 + (t & 1) * (HH * BB));
#pragma unroll
        for (int it = 0; it < 16; it++) {
            int idx = it * 256 + tid;
            int sidx = idx ^ ((((idx >> 10) & 3)) << 1);
            __builtin_amdgcn_global_load_lds(
                (const __attribute__((address_space(1))) void*)(hgr + sidx),
                (__attribute__((address_space(3))) void*)&h4[idx], 16, 0, 0);
        }
    }
    const float* brec = gbias + G3;
    const float bz = brec[i], br_ = brec[512 + i], bh = brec[1024 + i];
    __syncthreads();   // drains vmcnt for global_load_lds

    // mx loads — coalesced from mxT[t][j][b]
    const float* mxc = mxT + (size_t)t * G3 * BB;
    float mz = mxc[(size_t)i * BB + batch];
    float mr = mxc[(size_t)(512 + i) * BB + batch];
    float mh = mxc[(size_t)(1024 + i) * BB + batch];

    // ---- inner: 128 k per thread, 2 b128 reads + 12 FMA per k ----
    float az0 = 0.f, az1 = 0.f, az2 = 0.f, az3 = 0.f;
    float ar0 = 0.f, ar1 = 0.f, ar2 = 0.f, ar3 = 0.f;
    float ah0 = 0.f, ah1 = 0.f, ah2 = 0.f, ah3 = 0.f;
    const float4* wp  = wl4_dyn + ks * 1024 + jjs;
    const float4* hp2 = &h4[ks * 1024 + bqs];
#pragma unroll 4
    for (int kk = 0; kk < 128; kk++) {
        float4 w = wp[kk * 8];     // {wz,wr,wc,_} col jj, k=ks*128+kk (8-way broadcast)
        float4 h = hp2[kk * 8];    // h[k][bq*4 .. bq*4+3]
        az0 += w.x * h.x; az1 += w.x * h.y; az2 += w.x * h.z; az3 += w.x * h.w;
        ar0 += w.y * h.x; ar1 += w.y * h.y; ar2 += w.y * h.z; ar3 += w.y * h.w;
        ah0 += w.z * h.x; ah1 += w.z * h.y; ah2 += w.z * h.z; ah3 += w.z * h.w;
    }

    // ---- in-wave butterfly over ks lanes ----
    az0 += __shfl_xor(az0, 1); az1 += __shfl_xor(az1, 1);
    az2 += __shfl_xor(az2, 1); az3 += __shfl_xor(az3, 1);
    ar0 += __shfl_xor(ar0, 1); ar1 += __shfl_xor(ar1, 1);
    ar2 += __shfl_xor(ar2, 1); ar3 += __shfl_xor(ar3, 1);
    ah0 += __shfl_xor(ah0, 1); ah1 += __shfl_xor(ah1, 1);
    ah2 += __shfl_xor(ah2, 1); ah3 += __shfl_xor(ah3, 1);
    az0 += __shfl_xor(az0, 2); az1 += __shfl_xor(az1, 2);
    az2 += __shfl_xor(az2, 2); az3 += __shfl_xor(az3, 2);
    ar0 += __shfl_xor(ar0, 2); ar1 += __shfl_xor(ar1, 2);
    ar2 += __shfl_xor(ar2, 2); ar3 += __shfl_xor(ar3, 2);
    ah0 += __shfl_xor(ah0, 2); ah1 += __shfl_xor(ah1, 2);
    ah2 += __shfl_xor(ah2, 2); ah3 += __shfl_xor(ah3, 2);

    float azt = sel4_(az0, az1, az2, az3, ks);
    float art = sel4_(ar0, ar1, ar2, ar3, ks);
    float aht = sel4_(ah0, ah1, ah2, ah3, ks);

    float z = sigmoidf_(mz + azt + bz);
    float r = sigmoidf_(mr + art + br_);
    float c = tanhf(mh + r * (aht + bh));
    float hold = ((const float*)&h4[i * 8 + (bq ^ ((((i >> 7) & 3)) << 1))])[ks];
    float hn = z * hold + (1.f - z) * c;

    hg2[((t + 1) & 1) * (HH * BB) + i * BB + batch] = hn;   // coalesced across ks,bq

    // ---- hs store via LDS transpose (weights consumed -> reuse wl4_dyn region) ----
    __syncthreads();
    float* hstage = (float*)wl4_dyn;
    hstage[jj * 36 + batch] = hn;           // conflict-free (pad 36)
    __syncthreads();
    {
        int b2 = tid >> 3, ii = tid & 7;    // 32B-segment stores
        hs[((size_t)t * BB + b2) * HH + i0 + ii] = hstage[ii * 36 + b2];
    }
}

// ---------------- K3: sx[b][u][n] (upfront, r10 verbatim) ----------------
__global__ __launch_bounds__(256) void k_sx(const float* __restrict__ data,
                                            const float* __restrict__ w1,
                                            const float* __restrict__ w1b,
                                            float* __restrict__ sx) {
    int bx = blockIdx.x;
    int b = bx >> 4, ug = bx & 15;
    int n = threadIdx.x;
    float acc[8] = {0, 0, 0, 0, 0, 0, 0, 0};
    const float* dp = data + (size_t)b * TT * NF + n;
    for (int t = 0; t < TT; t++) {
        float x = dp[(size_t)t * NF];
#pragma unroll
        for (int uu = 0; uu < 8; uu++) acc[uu] += x * w1[t * TT + ug * 8 + uu];
    }
#pragma unroll
    for (int uu = 0; uu < 8; uu++) {
        int u = ug * 8 + uu;
        sx[((size_t)b * TT + u) * NF + n] = acc[uu] + w1b[u];
    }
}

// ---------------- K4: hp[r][u] = hs[r][:] @ w2 + w2b  (r10 verbatim) ----------------
__global__ __launch_bounds__(256) void k_hp(const float* __restrict__ hs,
                                            const float* __restrict__ w2,
                                            const float* __restrict__ w2b,
                                            float* __restrict__ hp) {
    __shared__ float hsl[8 * HH];   // 16KB
    int r0 = blockIdx.x * 8;
    int tid = threadIdx.x;
    for (int idx = tid; idx < 8 * HH; idx += 256)
        hsl[idx] = hs[(size_t)r0 * HH + idx];
    __syncthreads();
    int u = tid & 127, rh = tid >> 7;
    float acc[4] = {0, 0, 0, 0};
    for (int k = 0; k < HH; k++) {
        float w = w2[k * TT + u];
#pragma unroll
        for (int rr = 0; rr < 4; rr++) acc[rr] += hsl[(rh * 4 + rr) * HH + k] * w;
    }
    float wb = w2b[u];
#pragma unroll
    for (int rr = 0; rr < 4; rr++)
        hp[(size_t)(r0 + rh * 4 + rr) * TT + u] = acc[rr] + wb;
}

// ---------------- K5: fused score + softmax + output (rcp tanh + unroll) ----------------
__global__ __launch_bounds__(256) void k_attn(const float* __restrict__ data,
                                              const float* __restrict__ sx,
                                              const float* __restrict__ hp,
                                              const float* __restrict__ v_w,
                                              const float* __restrict__ v_b,
                                              float* __restrict__ out) {
    __shared__ float hv[TT];
    __shared__ float vv[TT];
    __shared__ float red[8];
    int r = blockIdx.x;
    int b = r & 31;
    int n = threadIdx.x;
    if (n < TT) {
        hv[n] = hp[(size_t)r * TT + n];
        vv[n] = v_w[n];
    }
    __syncthreads();
    float s = v_b[0];
    const float* sxp = sx + (size_t)b * TT * NF + n;
#pragma unroll 4
    for (int u = 0; u < TT; u++) {
        float e = tanh_fast(sxp[(size_t)u * NF] + hv[u]);
        s += vv[u] * e;
    }
    float m = s;
#pragma unroll
    for (int off = 32; off >= 1; off >>= 1) m = fmaxf(m, __shfl_xor(m, off));
    int lane = n & 63, wid = n >> 6;
    if (lane == 0) red[wid] = m;
    __syncthreads();
    float bm = fmaxf(fmaxf(red[0], red[1]), fmaxf(red[2], red[3]));
    float p = __expf(s - bm);
    float ps = p;
#pragma unroll
    for (int off = 32; off >= 1; off >>= 1) ps += __shfl_xor(ps, off);
    if (lane == 0) red[4 + wid] = ps;
    __syncthreads();
    float denom = red[4] + red[5] + red[6] + red[7];
    float alpha = p / denom;
    size_t idx = (size_t)r * NF + n;
    out[idx] = data[idx] * alpha;
}

extern "C" void kernel_launch(void* const* d_in, const int* in_sizes, int n_in,
                              void* d_out, int out_size, void* d_ws, size_t ws_size,
                              hipStream_t stream) {
    const float* data = (const float*)d_in[0];
    const float* h0   = (const float*)d_in[1];
    const float* gk   = (const float*)d_in[2];
    const float* rk   = (const float*)d_in[3];
    const float* gb   = (const float*)d_in[4];
    const float* w1   = (const float*)d_in[5];
    const float* w1b  = (const float*)d_in[6];
    const float* w2   = (const float*)d_in[7];
    const float* w2b  = (const float*)d_in[8];
    const float* vw   = (const float*)d_in[9];
    const float* vb   = (const float*)d_in[10];
    float* out = (float*)d_out;

    float* ws  = (float*)d_ws;
    float* mxT = ws;                    // 128*1536*32 = 6291456  ([t][j][b])
    float* hs  = mxT + 6291456;         // 128*32*512  = 2097152
    float* sxb = hs + 2097152;          // 32*128*256  = 1048576
    float* hpb = sxb + 1048576;         // 128*32*128  = 524288
    float* hg2 = hpb + 524288;          // 2*512*32    = 32768
    float4* rk4 = (float4*)(hg2 + 32768);   // 262144 float4 = 4 MB

    k_packinit<<<1088, 256, 0, stream>>>(rk, rk4, h0, hg2);
    k_mx<<<1536, 256, 0, stream>>>(data, gk, gb, mxT);

    for (int t = 0; t < TT; t++)
        k_gstep<<<NWG, 256, 65536, stream>>>(rk4, gb, mxT, hg2, hs, t);

    k_sx<<<512, 256, 0, stream>>>(data, w1, w1b, sxb);
    k_hp<<<512, 256, 0, stream>>>(hs, w2, w2b, hpb);
    k_attn<<<4096, 256, 0, stream>>>(data, sxb, hpb, vw, vb, out);
}

// Round 17
// 1167.287 us; speedup vs baseline: 1.0867x; 1.0074x over previous
//
#include <hip/hip_runtime.h>
#include <math.h>

#define BB 32     // batch
#define TT 128    // time steps
#define NF 256    // input features
#define HH 512    // hidden
#define G3 1536   // 3*H
#define NWG 64    // GRU workgroups (column partition)

__device__ __forceinline__ float sigmoidf_(float x) { return 1.f / (1.f + __expf(-x)); }
__device__ __forceinline__ float tanh_fast(float x) {
    float e = __expf(2.f * x);
    return 1.f - 2.f * __builtin_amdgcn_rcpf(e + 1.f);
}
__device__ __forceinline__ float sel4_(float a0, float a1, float a2, float a3, int s) {
    float s01 = (s & 1) ? a1 : a0;
    float s23 = (s & 1) ? a3 : a2;
    return (s & 2) ? s23 : s01;
}

// ---------------- K_UPFRONT: one launch, independent roles by block range ----------------
// [0,1024):    pack rk -> rk4 (swizzled, r10 layout)
// [1024,1088): hinit (transpose h0 -> hg2)
// [1088,4160): mxT — 6-way j-split (128 t x 4 bg x 6 jth), 1 j/thread, 12 blocks/CU
// [4160,4672): sx
__global__ __launch_bounds__(256) void k_upfront(const float* __restrict__ rk,
                                                 float4* __restrict__ rk4,
                                                 const float* __restrict__ h0,
                                                 float* __restrict__ hg2,
                                                 const float* __restrict__ data,
                                                 const float* __restrict__ gk,
                                                 const float* __restrict__ bias_in,
                                                 float* __restrict__ mxT,
                                                 const float* __restrict__ w1,
                                                 const float* __restrict__ w1b,
                                                 float* __restrict__ sx) {
    int bid = blockIdx.x;
    int tid = threadIdx.x;

    if (bid < 1024) {
        // ---- pack role ----
        int gidx = bid * 256 + tid;   // 262144
        int wg = gidx >> 12;
        int idx = gidx & 4095;
        int k = idx >> 3, s = idx & 7;
        int jjL = s ^ (((k >> 7) & 3) << 1);
        const float* r = rk + (size_t)k * G3 + wg * 8 + jjL;
        rk4[gidx] = make_float4(r[0], r[512], r[1024], 0.f);

    } else if (bid < 1088) {
        // ---- hinit role ----
        int idx = (bid - 1024) * 256 + tid;   // 16384
        int i = idx & 511, b = idx >> 9;
        hg2[i * BB + b] = h0[b * HH + i];

    } else if (bid < 4160) {
        // ---- mx role: 6-way j-split; k-loop order bit-identical per (j,b) ----
        __shared__ __align__(16) float xs[NF * 8];   // [k][bb]
        int bx = bid - 1088;                  // 0..3071
        int t = bx / 24;
        int rem = bx - t * 24;
        int bg = rem / 6;
        int jth = rem - bg * 6;
        int b0 = bg * 8;
        for (int idx = tid; idx < 8 * NF; idx += 256) {
            int bb = idx >> 8, k = idx & 255;
            xs[k * 8 + bb] = data[((size_t)(b0 + bb) * TT + t) * NF + k];
        }
        __syncthreads();
        float acc[8];
#pragma unroll
        for (int bb = 0; bb < 8; bb++) acc[bb] = 0.f;

        const float* gkc = gk + jth * 256 + tid;
        for (int k = 0; k < NF; k++) {
            float4 xa = *(const float4*)&xs[k * 8];
            float4 xb = *(const float4*)&xs[k * 8 + 4];
            float g = gkc[(size_t)k * G3];
            acc[0] += g * xa.x; acc[1] += g * xa.y; acc[2] += g * xa.z; acc[3] += g * xa.w;
            acc[4] += g * xb.x; acc[5] += g * xb.y; acc[6] += g * xb.z; acc[7] += g * xb.w;
        }
        int j = jth * 256 + tid;
        float bi = bias_in[j];
#pragma unroll
        for (int bb = 0; bb < 8; bb++)
            mxT[((size_t)t * G3 + j) * BB + b0 + bb] = acc[bb] + bi;   // [t][j][b]

    } else {
        // ---- sx role (r10 verbatim body) ----
        int bx = bid - 4160;                  // 0..511
        int b = bx >> 4, ug = bx & 15;
        int n = tid;
        float acc[8] = {0, 0, 0, 0, 0, 0, 0, 0};
        const float* dp = data + (size_t)b * TT * NF + n;
        for (int t = 0; t < TT; t++) {
            float x = dp[(size_t)t * NF];
#pragma unroll
            for (int uu = 0; uu < 8; uu++) acc[uu] += x * w1[t * TT + ug * 8 + uu];
        }
#pragma unroll
        for (int uu = 0; uu < 8; uu++) {
            int u = ug * 8 + uu;
            sx[((size_t)b * TT + u) * NF + n] = acc[uu] + w1b[u];
        }
    }
}

// ---------------- K2: ONE GRU STEP — r14/r16 proven kernel VERBATIM ----------------
extern __shared__ float4 wl4_dyn[];   // 4096 float4 = 64 KB, r10 swizzled weight layout

__global__ __launch_bounds__(256, 1) void k_gstep(const float4* __restrict__ rk4,
                                                  const float* __restrict__ gbias,
                                                  const float* __restrict__ mxT,
                                                  float* __restrict__ hg2,
                                                  float* __restrict__ hs,
                                                  int t) {
    __shared__ __align__(16) float4 h4[HH * 8];   // 64 KB: h[k][batch-quad], swizzled
    const int tid = threadIdx.x;
    const int wg  = blockIdx.x;
    const int jj  = tid >> 5;          // 0..7 column within slice
    const int bq  = (tid >> 2) & 7;    // 0..7 batch quad
    const int ks  = tid & 3;           // 0..3 k-split (128 k each)
    const int i0  = wg * 8;
    const int i   = i0 + jj;
    const int batch = bq * 4 + ks;
    const int jjs = jj ^ (ks << 1);    // swizzled weight slot for this thread's k-range
    const int bqs = bq ^ (ks << 1);    // swizzled h slot for this thread's k-range

    // ---- stage weights: async global->LDS, linear dest (prepacked swizzle) ----
    {
        const float4* src = rk4 + (size_t)wg * 4096;
#pragma unroll
        for (int it = 0; it < 16; it++) {
            int idx = it * 256 + tid;
            __builtin_amdgcn_global_load_lds(
                (const __attribute__((address_space(1))) void*)(src + idx),
                (__attribute__((address_space(3))) void*)&wl4_dyn[idx], 16, 0, 0);
        }
    }
    // ---- stage h: linear LDS dest, PRE-SWIZZLED global source (m173 pattern) ----
    {
        const float4* hgr = (const float4*)(hg2 + (t & 1) * (HH * BB));
#pragma unroll
        for (int it = 0; it < 16; it++) {
            int idx = it * 256 + tid;
            int sidx = idx ^ ((((idx >> 10) & 3)) << 1);
            __builtin_amdgcn_global_load_lds(
                (const __attribute__((address_space(1))) void*)(hgr + sidx),
                (__attribute__((address_space(3))) void*)&h4[idx], 16, 0, 0);
        }
    }
    const float* brec = gbias + G3;
    const float bz = brec[i], br_ = brec[512 + i], bh = brec[1024 + i];
    __syncthreads();   // drains vmcnt for global_load_lds

    // mx loads — coalesced from mxT[t][j][b]
    const float* mxc = mxT + (size_t)t * G3 * BB;
    float mz = mxc[(size_t)i * BB + batch];
    float mr = mxc[(size_t)(512 + i) * BB + batch];
    float mh = mxc[(size_t)(1024 + i) * BB + batch];

    // ---- inner: 128 k per thread, 2 b128 reads + 12 FMA per k ----
    float az0 = 0.f, az1 = 0.f, az2 = 0.f, az3 = 0.f;
    float ar0 = 0.f, ar1 = 0.f, ar2 = 0.f, ar3 = 0.f;
    float ah0 = 0.f, ah1 = 0.f, ah2 = 0.f, ah3 = 0.f;
    const float4* wp  = wl4_dyn + ks * 1024 + jjs;
    const float4* hp2 = &h4[ks * 1024 + bqs];
#pragma unroll 4
    for (int kk = 0; kk < 128; kk++) {
        float4 w = wp[kk * 8];     // {wz,wr,wc,_} col jj, k=ks*128+kk (8-way broadcast)
        float4 h = hp2[kk * 8];    // h[k][bq*4 .. bq*4+3]
        az0 += w.x * h.x; az1 += w.x * h.y; az2 += w.x * h.z; az3 += w.x * h.w;
        ar0 += w.y * h.x; ar1 += w.y * h.y; ar2 += w.y * h.z; ar3 += w.y * h.w;
        ah0 += w.z * h.x; ah1 += w.z * h.y; ah2 += w.z * h.z; ah3 += w.z * h.w;
    }

    // ---- in-wave butterfly over ks lanes ----
    az0 += __shfl_xor(az0, 1); az1 += __shfl_xor(az1, 1);
    az2 += __shfl_xor(az2, 1); az3 += __shfl_xor(az3, 1);
    ar0 += __shfl_xor(ar0, 1); ar1 += __shfl_xor(ar1, 1);
    ar2 += __shfl_xor(ar2, 1); ar3 += __shfl_xor(ar3, 1);
    ah0 += __shfl_xor(ah0, 1); ah1 += __shfl_xor(ah1, 1);
    ah2 += __shfl_xor(ah2, 1); ah3 += __shfl_xor(ah3, 1);
    az0 += __shfl_xor(az0, 2); az1 += __shfl_xor(az1, 2);
    az2 += __shfl_xor(az2, 2); az3 += __shfl_xor(az3, 2);
    ar0 += __shfl_xor(ar0, 2); ar1 += __shfl_xor(ar1, 2);
    ar2 += __shfl_xor(ar2, 2); ar3 += __shfl_xor(ar3, 2);
    ah0 += __shfl_xor(ah0, 2); ah1 += __shfl_xor(ah1, 2);
    ah2 += __shfl_xor(ah2, 2); ah3 += __shfl_xor(ah3, 2);

    float azt = sel4_(az0, az1, az2, az3, ks);
    float art = sel4_(ar0, ar1, ar2, ar3, ks);
    float aht = sel4_(ah0, ah1, ah2, ah3, ks);

    float z = sigmoidf_(mz + azt + bz);
    float r = sigmoidf_(mr + art + br_);
    float c = tanhf(mh + r * (aht + bh));
    float hold = ((const float*)&h4[i * 8 + (bq ^ ((((i >> 7) & 3)) << 1))])[ks];
    float hn = z * hold + (1.f - z) * c;

    hg2[((t + 1) & 1) * (HH * BB) + i * BB + batch] = hn;   // coalesced across ks,bq

    // ---- hs store via LDS transpose (weights consumed -> reuse wl4_dyn region) ----
    __syncthreads();
    float* hstage = (float*)wl4_dyn;
    hstage[jj * 36 + batch] = hn;           // conflict-free (pad 36)
    __syncthreads();
    {
        int b2 = tid >> 3, ii = tid & 7;    // 32B-segment stores
        hs[((size_t)t * BB + b2) * HH + i0 + ii] = hstage[ii * 36 + b2];
    }
}

// ---------------- K4: hp[r][u] = hs[r][:] @ w2 + w2b  (r10 verbatim) ----------------
__global__ __launch_bounds__(256) void k_hp(const float* __restrict__ hs,
                                            const float* __restrict__ w2,
                                            const float* __restrict__ w2b,
                                            float* __restrict__ hp) {
    __shared__ float hsl[8 * HH];   // 16KB
    int r0 = blockIdx.x * 8;
    int tid = threadIdx.x;
    for (int idx = tid; idx < 8 * HH; idx += 256)
        hsl[idx] = hs[(size_t)r0 * HH + idx];
    __syncthreads();
    int u = tid & 127, rh = tid >> 7;
    float acc[4] = {0, 0, 0, 0};
    for (int k = 0; k < HH; k++) {
        float w = w2[k * TT + u];
#pragma unroll
        for (int rr = 0; rr < 4; rr++) acc[rr] += hsl[(rh * 4 + rr) * HH + k] * w;
    }
    float wb = w2b[u];
#pragma unroll
    for (int rr = 0; rr < 4; rr++)
        hp[(size_t)(r0 + rh * 4 + rr) * TT + u] = acc[rr] + wb;
}

// ---------------- K5: fused score + softmax + output (rcp tanh + unroll) ----------------
__global__ __launch_bounds__(256) void k_attn(const float* __restrict__ data,
                                              const float* __restrict__ sx,
                                              const float* __restrict__ hp,
                                              const float* __restrict__ v_w,
                                              const float* __restrict__ v_b,
                                              float* __restrict__ out) {
    __shared__ float hv[TT];
    __shared__ float vv[TT];
    __shared__ float red[8];
    int r = blockIdx.x;
    int b = r & 31;
    int n = threadIdx.x;
    if (n < TT) {
        hv[n] = hp[(size_t)r * TT + n];
        vv[n] = v_w[n];
    }
    __syncthreads();
    float s = v_b[0];
    const float* sxp = sx + (size_t)b * TT * NF + n;
#pragma unroll 4
    for (int u = 0; u < TT; u++) {
        float e = tanh_fast(sxp[(size_t)u * NF] + hv[u]);
        s += vv[u] * e;
    }
    float m = s;
#pragma unroll
    for (int off = 32; off >= 1; off >>= 1) m = fmaxf(m, __shfl_xor(m, off));
    int lane = n & 63, wid = n >> 6;
    if (lane == 0) red[wid] = m;
    __syncthreads();
    float bm = fmaxf(fmaxf(red[0], red[1]), fmaxf(red[2], red[3]));
    float p = __expf(s - bm);
    float ps = p;
#pragma unroll
    for (int off = 32; off >= 1; off >>= 1) ps += __shfl_xor(ps, off);
    if (lane == 0) red[4 + wid] = ps;
    __syncthreads();
    float denom = red[4] + red[5] + red[6] + red[7];
    float alpha = p / denom;
    size_t idx = (size_t)r * NF + n;
    out[idx] = data[idx] * alpha;
}

extern "C" void kernel_launch(void* const* d_in, const int* in_sizes, int n_in,
                              void* d_out, int out_size, void* d_ws, size_t ws_size,
                              hipStream_t stream) {
    const float* data = (const float*)d_in[0];
    const float* h0   = (const float*)d_in[1];
    const float* gk   = (const float*)d_in[2];
    const float* rk   = (const float*)d_in[3];
    const float* gb   = (const float*)d_in[4];
    const float* w1   = (const float*)d_in[5];
    const float* w1b  = (const float*)d_in[6];
    const float* w2   = (const float*)d_in[7];
    const float* w2b  = (const float*)d_in[8];
    const float* vw   = (const float*)d_in[9];
    const float* vb   = (const float*)d_in[10];
    float* out = (float*)d_out;

    float* ws  = (float*)d_ws;
    float* mxT = ws;                    // 128*1536*32 = 6291456  ([t][j][b])
    float* hs  = mxT + 6291456;         // 128*32*512  = 2097152
    float* sxb = hs + 2097152;          // 32*128*256  = 1048576
    float* hpb = sxb + 1048576;         // 128*32*128  = 524288
    float* hg2 = hpb + 524288;          // 2*512*32    = 32768
    float4* rk4 = (float4*)(hg2 + 32768);   // 262144 float4 = 4 MB

    k_upfront<<<4672, 256, 0, stream>>>(rk, rk4, h0, hg2,
                                        data, gk, gb, mxT, w1, w1b, sxb);

    for (int t = 0; t < TT; t++)
        k_gstep<<<NWG, 256, 65536, stream>>>(rk4, gb, mxT, hg2, hs, t);

    k_hp<<<512, 256, 0, stream>>>(hs, w2, w2b, hpb);
    k_attn<<<4096, 256, 0, stream>>>(data, sxb, hpb, vw, vb, out);
}